// Round 2
// baseline (412.861 us; speedup 1.0000x reference)
//
#include <hip/hip_runtime.h>
#include <hip/hip_bf16.h>

#define B_ROWS 65536
#define D_DIM  1024
#define NC     120   // 100 expert units + 2*10 gate logits
#define MBLK   64    // rows per workgroup
#define CSTR   121   // epilogue C stride (odd -> conflict-light)

typedef __attribute__((ext_vector_type(4))) float f32x4;
typedef __attribute__((ext_vector_type(8))) short bf16x8;

__device__ __forceinline__ unsigned short f2bf(float f) {
  union { float f; unsigned u; } v; v.f = f;
  unsigned r = v.u + 0x7FFFu + ((v.u >> 16) & 1u);  // RNE
  return (unsigned short)(r >> 16);
}

__device__ __forceinline__ void gload_lds16(const short* g, short* l) {
  // each lane: 16B from its own global addr -> LDS wave-uniform base + lane*16
  __builtin_amdgcn_global_load_lds(
      (const __attribute__((address_space(1))) void*)g,
      (__attribute__((address_space(3))) void*)l, 16, 0, 0);
}

// Pack expert_w [10][1024][10] and gate_w [2][1024][10] into bf16 Wt[c][d]
// (B^T layout), c in 0..127, cols 120..127 zero.
__global__ __launch_bounds__(256) void pack_w(const float* __restrict__ ew,
                                              const float* __restrict__ gw,
                                              short* __restrict__ wt) {
  int idx = blockIdx.x * 256 + threadIdx.x;   // 128*1024
  int c = idx >> 10, d = idx & 1023;
  float v = 0.f;
  if (c < 100) {
    int e = c / 10, u = c % 10;
    v = ew[(e * D_DIM + d) * 10 + u];
  } else if (c < NC) {
    int q = c - 100; int t = q / 10, e = q % 10;
    v = gw[(t * D_DIM + d) * 10 + e];
  }
  wt[c * D_DIM + d] = (short)f2bf(v);
}

union Smem {
  short Bq[2][8192];     // 2 x 16KB: B chunk, row c -> shorts [c*64 + p*8 .. +8),
                         // position p holds global k-group g = p ^ (c&7)
  float C[MBLK * CSTR];  // 30976 B epilogue scratch (union: used after K-loop)
};

__global__ __launch_bounds__(256, 4) void mmoe_main(
    const float* __restrict__ x, const short* __restrict__ wt,
    const float* __restrict__ eb, const float* __restrict__ gb,
    const float* __restrict__ ctr_w, const float* __restrict__ ctr_b,
    const float* __restrict__ cvr_w, const float* __restrict__ cvr_b,
    float* __restrict__ out) {
  __shared__ Smem sm;
  const int tid  = threadIdx.x;
  const int wave = tid >> 6, lane = tid & 63;
  const int lhi  = lane >> 4, llo = lane & 15;   // quad, row-in-tile
  const int m0   = blockIdx.x * MBLK;

  // A-fragment source: this lane's row, 8 consecutive floats per k-step
  const float* xrow = x + (size_t)(m0 + wave * 16 + llo) * D_DIM + lhi * 8;

  f32x4 acc[8];
  #pragma unroll
  for (int i = 0; i < 8; ++i) acc[i] = (f32x4){0.f, 0.f, 0.f, 0.f};

  float4 pa[2][4];

  // ---- prologue: stage B chunk 0, prefetch A chunk 0
  #pragma unroll
  for (int j = 0; j < 4; ++j) {
    const int slot = j * 256 + wave * 64 + lane;
    const int c = slot >> 3, p = slot & 7;
    const int g = p ^ (c & 7);
    gload_lds16(wt + c * D_DIM + g * 8,
                &sm.Bq[0][(j * 256 + wave * 64) * 8]);
  }
  pa[0][0] = *(const float4*)(xrow + 0);
  pa[0][1] = *(const float4*)(xrow + 4);
  pa[0][2] = *(const float4*)(xrow + 32);
  pa[0][3] = *(const float4*)(xrow + 36);
  __syncthreads();

  for (int ch = 0; ch < 16; ++ch) {
    const int cur = ch & 1;
    if (ch < 15) {
      const int k1 = (ch + 1) * 64;
      #pragma unroll
      for (int j = 0; j < 4; ++j) {
        const int slot = j * 256 + wave * 64 + lane;
        const int c = slot >> 3, p = slot & 7;
        const int g = p ^ (c & 7);
        gload_lds16(wt + c * D_DIM + k1 + g * 8,
                    &sm.Bq[cur ^ 1][(j * 256 + wave * 64) * 8]);
      }
      pa[cur ^ 1][0] = *(const float4*)(xrow + k1);
      pa[cur ^ 1][1] = *(const float4*)(xrow + k1 + 4);
      pa[cur ^ 1][2] = *(const float4*)(xrow + k1 + 32);
      pa[cur ^ 1][3] = *(const float4*)(xrow + k1 + 36);
    }
    // ---- convert this chunk's A (registers only)
    bf16x8 af0, af1;
    {
      const float4 a = pa[cur][0], b = pa[cur][1];
      af0[0] = (short)f2bf(a.x); af0[1] = (short)f2bf(a.y);
      af0[2] = (short)f2bf(a.z); af0[3] = (short)f2bf(a.w);
      af0[4] = (short)f2bf(b.x); af0[5] = (short)f2bf(b.y);
      af0[6] = (short)f2bf(b.z); af0[7] = (short)f2bf(b.w);
      const float4 c2 = pa[cur][2], d2 = pa[cur][3];
      af1[0] = (short)f2bf(c2.x); af1[1] = (short)f2bf(c2.y);
      af1[2] = (short)f2bf(c2.z); af1[3] = (short)f2bf(c2.w);
      af1[4] = (short)f2bf(d2.x); af1[5] = (short)f2bf(d2.y);
      af1[6] = (short)f2bf(d2.z); af1[7] = (short)f2bf(d2.w);
    }
    // ---- MFMA over 2 k-steps x 8 col-tiles
    const int swz = llo & 7;
    #pragma unroll
    for (int half = 0; half < 2; ++half) {
      const bf16x8 a = half ? af1 : af0;
      const int g0 = half * 4 + lhi;
      const int p  = g0 ^ swz;
      #pragma unroll
      for (int ct = 0; ct < 8; ++ct) {
        const bf16x8 bfr = *(const bf16x8*)&sm.Bq[cur][(ct * 16 + llo) * 64 + p * 8];
        acc[ct] = __builtin_amdgcn_mfma_f32_16x16x32_bf16(a, bfr, acc[ct], 0, 0, 0);
      }
    }
    __syncthreads();
  }

  // ---- C frags -> LDS (C/D: col=lane&15, row=quad*4+reg)
  #pragma unroll
  for (int ct = 0; ct < 8; ++ct) {
    const int col = ct * 16 + llo;
    if (col < NC) {
      #pragma unroll
      for (int r = 0; r < 4; ++r)
        sm.C[(wave * 16 + lhi * 4 + r) * CSTR + col] = acc[ct][r];
    }
  }
  __syncthreads();

  // ---- epilogue: (row, task) per thread
  if (tid < 128) {
    const int task = tid >> 6, row = tid & 63;
    const float* crow = &sm.C[row * CSTR];
    const float* tw = task ? cvr_w : ctr_w;
    const float tb = task ? cvr_b[0] : ctr_b[0];
    float s[10];
    #pragma unroll
    for (int e = 0; e < 10; ++e) {
      float a = 0.f;
      #pragma unroll
      for (int u = 0; u < 10; ++u) {
        float v = fmaxf(crow[e * 10 + u] + eb[e * 10 + u], 0.f);
        a = fmaf(v, tw[u], a);
      }
      s[e] = a;
    }
    float gl[10], mx = -1e30f;
    #pragma unroll
    for (int e = 0; e < 10; ++e) {
      gl[e] = crow[100 + task * 10 + e] + gb[task * 10 + e];
      mx = fmaxf(mx, gl[e]);
    }
    float den = 0.f, num = 0.f;
    #pragma unroll
    for (int e = 0; e < 10; ++e) {
      float pz = __expf(gl[e] - mx);
      den += pz; num = fmaf(pz, s[e], num);
    }
    const float z = num / den + tb;
    out[task * B_ROWS + m0 + row] = 1.f / (1.f + __expf(-z));
  }
}

extern "C" void kernel_launch(void* const* d_in, const int* in_sizes, int n_in,
                              void* d_out, int out_size, void* d_ws, size_t ws_size,
                              hipStream_t stream) {
  const float* x     = (const float*)d_in[0];
  const float* ew    = (const float*)d_in[3];
  const float* eb    = (const float*)d_in[4];
  const float* gw    = (const float*)d_in[5];
  const float* gb    = (const float*)d_in[6];
  const float* ctr_w = (const float*)d_in[7];
  const float* ctr_b = (const float*)d_in[8];
  const float* cvr_w = (const float*)d_in[9];
  const float* cvr_b = (const float*)d_in[10];
  float* out = (float*)d_out;
  short* wt  = (short*)d_ws;  // 128*1024 bf16 = 256 KB

  pack_w<<<512, 256, 0, stream>>>(ew, gw, wt);
  mmoe_main<<<B_ROWS / MBLK, 256, 0, stream>>>(x, wt, eb, gb, ctr_w, ctr_b,
                                               cvr_w, cvr_b, out);
}

// Round 3
// 412.363 us; speedup vs baseline: 1.0012x; 1.0012x over previous
//
#include <hip/hip_runtime.h>
#include <hip/hip_bf16.h>

#define B_ROWS 65536
#define D_DIM  1024
#define NC     120   // 100 expert units + 2*10 gate logits
#define CSTR   121   // epilogue LDS stride (121 mod 32 = 25, gcd(25,32)=1 -> conflict-free row scan)

typedef __attribute__((ext_vector_type(4))) float f32x4;
typedef __attribute__((ext_vector_type(8))) short bf16x8;

__device__ __forceinline__ unsigned short f2bf(float f) {
  union { float f; unsigned u; } v; v.f = f;
  unsigned r = v.u + 0x7FFFu + ((v.u >> 16) & 1u);  // RNE
  return (unsigned short)(r >> 16);
}

__device__ __forceinline__ short f2bfs(float f) {
  __hip_bfloat16 h = __float2bfloat16(f);   // hw cvt on gfx950
  return (short)__builtin_bit_cast(unsigned short, h);
}

// Pack expert_w [10][1024][10] and gate_w [2][1024][10] into bf16 Wt[c][d]
// (B^T layout), c in 0..127, cols 120..127 zero.
__global__ __launch_bounds__(256) void pack_w(const float* __restrict__ ew,
                                              const float* __restrict__ gw,
                                              short* __restrict__ wt) {
  int idx = blockIdx.x * 256 + threadIdx.x;   // 128*1024
  int c = idx >> 10, d = idx & 1023;
  float v = 0.f;
  if (c < 100) {
    int e = c / 10, u = c % 10;
    v = ew[(e * D_DIM + d) * 10 + u];
  } else if (c < NC) {
    int q = c - 100; int t = q / 10, e = q % 10;
    v = gw[(t * D_DIM + d) * 10 + e];
  }
  wt[c * D_DIM + d] = (short)f2bf(v);
}

// Block = 4 waves; each wave independently computes 32 rows (2 row-tiles of 16).
// B fragments read straight from global (wt is 240KB -> L1/L2 resident).
// No barriers in the K-loop; depth-1 register double-buffer on A and B.
__global__ __launch_bounds__(256, 2) void mmoe_main(
    const float* __restrict__ x, const short* __restrict__ wt,
    const float* __restrict__ eb, const float* __restrict__ gb,
    const float* __restrict__ ctr_w, const float* __restrict__ ctr_b,
    const float* __restrict__ cvr_w, const float* __restrict__ cvr_b,
    float* __restrict__ out) {
  __shared__ float C[4][32 * CSTR];   // 61952 B
  const int tid  = threadIdx.x;
  const int wave = tid >> 6, lane = tid & 63;
  const int lhi  = lane >> 4, llo = lane & 15;
  const int m0   = blockIdx.x * 128 + wave * 32;

  const float* xr0 = x + (size_t)(m0 + llo) * D_DIM + lhi * 8;       // row-tile 0
  const float* xr1 = xr0 + (size_t)16 * D_DIM;                       // row-tile 1
  const short* bb  = wt + llo * D_DIM + lhi * 8;                     // + ct*16*1024 + ks*32

  f32x4 acc[2][8];
  #pragma unroll
  for (int rt = 0; rt < 2; ++rt)
    #pragma unroll
    for (int ct = 0; ct < 8; ++ct) acc[rt][ct] = (f32x4){0.f, 0.f, 0.f, 0.f};

  float4 pa[2][2][2];   // [buf][rt][half]
  uint4  pb[2][8];      // [buf][ct]

  // prologue: load k-step 0 into buf 0
  pa[0][0][0] = *(const float4*)(xr0);
  pa[0][0][1] = *(const float4*)(xr0 + 4);
  pa[0][1][0] = *(const float4*)(xr1);
  pa[0][1][1] = *(const float4*)(xr1 + 4);
  #pragma unroll
  for (int ct = 0; ct < 8; ++ct)
    pb[0][ct] = *(const uint4*)(bb + ct * 16 * D_DIM);

  #pragma unroll 2
  for (int ks = 0; ks < 32; ++ks) {
    const int cur = ks & 1, nxt = cur ^ 1;
    const int kn = ((ks + 1) & 31) * 32;   // last iter harmlessly reloads step 0
    pa[nxt][0][0] = *(const float4*)(xr0 + kn);
    pa[nxt][0][1] = *(const float4*)(xr0 + kn + 4);
    pa[nxt][1][0] = *(const float4*)(xr1 + kn);
    pa[nxt][1][1] = *(const float4*)(xr1 + kn + 4);
    #pragma unroll
    for (int ct = 0; ct < 8; ++ct)
      pb[nxt][ct] = *(const uint4*)(bb + ct * 16 * D_DIM + kn);

    bf16x8 af[2];
    #pragma unroll
    for (int rt = 0; rt < 2; ++rt) {
      const float4 a = pa[cur][rt][0], b = pa[cur][rt][1];
      af[rt][0] = f2bfs(a.x); af[rt][1] = f2bfs(a.y);
      af[rt][2] = f2bfs(a.z); af[rt][3] = f2bfs(a.w);
      af[rt][4] = f2bfs(b.x); af[rt][5] = f2bfs(b.y);
      af[rt][6] = f2bfs(b.z); af[rt][7] = f2bfs(b.w);
    }
    #pragma unroll
    for (int ct = 0; ct < 8; ++ct) {
      const bf16x8 bf = __builtin_bit_cast(bf16x8, pb[cur][ct]);
      acc[0][ct] = __builtin_amdgcn_mfma_f32_16x16x32_bf16(af[0], bf, acc[0][ct], 0, 0, 0);
      acc[1][ct] = __builtin_amdgcn_mfma_f32_16x16x32_bf16(af[1], bf, acc[1][ct], 0, 0, 0);
    }
  }

  // ---- C frags -> per-wave LDS (C/D: col=lane&15, row=quad*4+reg)
  #pragma unroll
  for (int rt = 0; rt < 2; ++rt) {
    #pragma unroll
    for (int ct = 0; ct < 8; ++ct) {
      const int col = ct * 16 + llo;
      if (col < NC) {
        #pragma unroll
        for (int r = 0; r < 4; ++r)
          C[wave][(rt * 16 + lhi * 4 + r) * CSTR + col] = acc[rt][ct][r];
      }
    }
  }
  __syncthreads();

  // ---- epilogue: lane = task*32 + row (all 64 lanes active)
  {
    const int task = lane >> 5, row = lane & 31;
    const float* crow = &C[wave][row * CSTR];
    const float* tw = task ? cvr_w : ctr_w;
    const float tb = task ? cvr_b[0] : ctr_b[0];
    float s[10];
    #pragma unroll
    for (int e = 0; e < 10; ++e) {
      float a = 0.f;
      #pragma unroll
      for (int u = 0; u < 10; ++u) {
        float v = fmaxf(crow[e * 10 + u] + eb[e * 10 + u], 0.f);
        a = fmaf(v, tw[u], a);
      }
      s[e] = a;
    }
    float gl[10], mx = -1e30f;
    #pragma unroll
    for (int e = 0; e < 10; ++e) {
      gl[e] = crow[100 + task * 10 + e] + gb[task * 10 + e];
      mx = fmaxf(mx, gl[e]);
    }
    float den = 0.f, num = 0.f;
    #pragma unroll
    for (int e = 0; e < 10; ++e) {
      float pz = __expf(gl[e] - mx);
      den += pz; num = fmaf(pz, s[e], num);
    }
    const float z = num / den + tb;
    out[task * B_ROWS + m0 + row] = 1.f / (1.f + __expf(-z));
  }
}

extern "C" void kernel_launch(void* const* d_in, const int* in_sizes, int n_in,
                              void* d_out, int out_size, void* d_ws, size_t ws_size,
                              hipStream_t stream) {
  const float* x     = (const float*)d_in[0];
  const float* ew    = (const float*)d_in[3];
  const float* eb    = (const float*)d_in[4];
  const float* gw    = (const float*)d_in[5];
  const float* gb    = (const float*)d_in[6];
  const float* ctr_w = (const float*)d_in[7];
  const float* ctr_b = (const float*)d_in[8];
  const float* cvr_w = (const float*)d_in[9];
  const float* cvr_b = (const float*)d_in[10];
  float* out = (float*)d_out;
  short* wt  = (short*)d_ws;  // 128*1024 bf16 = 256 KB

  pack_w<<<512, 256, 0, stream>>>(ew, gw, wt);
  mmoe_main<<<B_ROWS / 128, 256, 0, stream>>>(x, wt, eb, gb, ctr_w, ctr_b,
                                              cvr_w, cvr_b, out);
}